// Round 8
// baseline (708.470 us; speedup 1.0000x reference)
//
#include <hip/hip_runtime.h>
#include <stdint.h>

// instant-ngp multilevel hash-grid encoding, MI355X — phase-split + paired loads.
//
// R2: one kernel, 700us, FETCH 2.04GB (16 tables thrash L2).
// R4: grid.sync phases: FETCH 575MB but 2240us (barrier drain + 32B RMW writes).
// R5: kernel-per-hash-level + staged merge: 681us. Dense kernel = new bottleneck
//     (253us, FETCH 406MB); per-level cost ~31-43us regardless of residency ->
//     vector-memory probe bound (8x 8B divergent gathers / point / level).
// R6 (this): halve gather instructions where the x-pair is contiguous:
//     dense {i0,i0+1} aligned when i0 even; hash PRIMES[0]==1 -> {J,J^1} aligned
//     pair when ix even. One float4 gather replaces two float2 (-25% probes avg).
//     PPT=2 in hash kernels (MLP), float4 PPT=2 merge.

struct EmbPtrs { const float2* p[16]; };

constexpr int BLOCK = 256;
constexpr int kRes[16] = {16,20,25,32,40,50,64,80,101,128,161,203,256,322,406,512};
constexpr uint32_t P1 = 2654435761u, P2 = 805459861u;
constexpr uint32_t HMASK = (1u << 19) - 1u;

struct Tri {
    int ix, iy, iz;
    float wx[2], wy[2], wz[2];
    bool vx[2], vy[2], vz[2];
};

template<int RES_>
__device__ __forceinline__ Tri tri_setup(float px, float py, float pz)
{
    Tri s;
    const float rh = (float)RES_ * 0.5f;
    const float xp = (px + 1.0f) * rh - 0.5f;   // match reference op order
    const float yp = (py + 1.0f) * rh - 0.5f;
    const float zp = (pz + 1.0f) * rh - 0.5f;
    const float fx = floorf(xp), fy = floorf(yp), fz = floorf(zp);
    s.ix = (int)fx; s.iy = (int)fy; s.iz = (int)fz;
    const float tx = xp - fx, ty = yp - fy, tz = zp - fz;
    s.wx[0] = 1.0f - tx; s.wx[1] = tx;
    s.wy[0] = 1.0f - ty; s.wy[1] = ty;
    s.wz[0] = 1.0f - tz; s.wz[1] = tz;
    s.vx[0] = (s.ix   >= 0) && (s.ix   < RES_); s.vx[1] = (s.ix+1 >= 0) && (s.ix+1 < RES_);
    s.vy[0] = (s.iy   >= 0) && (s.iy   < RES_); s.vy[1] = (s.iy+1 >= 0) && (s.iy+1 < RES_);
    s.vz[0] = (s.iz   >= 0) && (s.iz   < RES_); s.vz[1] = (s.iz+1 >= 0) && (s.iz+1 < RES_);
    return s;
}

template<int RES_>
__device__ __forceinline__ float2 dense_feat(const float2* __restrict__ tab,
                                             float px, float py, float pz)
{
    const Tri s = tri_setup<RES_>(px, py, pz);
    constexpr int r2 = RES_ * RES_;
    const int base = s.ix + s.iy * RES_ + s.iz * r2;
    float ax = 0.0f, ay = 0.0f;
#pragma unroll
    for (int k = 0; k < 2; ++k)
#pragma unroll
    for (int j = 0; j < 2; ++j) {
        const bool vyz = s.vy[j] && s.vz[k];
        const float wyz = s.wy[j] * s.wz[k];
        const int i0 = base + j * RES_ + k * r2;
        const float w0 = (vyz && s.vx[0]) ? s.wx[0] * wyz : 0.0f;
        const float w1 = (vyz && s.vx[1]) ? s.wx[1] * wyz : 0.0f;
        if (vyz && s.vx[0] && s.vx[1] && !(i0 & 1)) {
            const float4 q = *(const float4*)(tab + i0);   // 16B aligned, both corners
            ax = fmaf(q.x, w0, ax); ay = fmaf(q.y, w0, ay);
            ax = fmaf(q.z, w1, ax); ay = fmaf(q.w, w1, ay);
        } else {
            const uint32_t a0 = (vyz && s.vx[0]) ? (uint32_t)i0       : 0u;
            const uint32_t a1 = (vyz && s.vx[1]) ? (uint32_t)(i0 + 1) : 0u;
            const float2 e0 = tab[a0];
            const float2 e1 = tab[a1];
            ax = fmaf(e0.x, w0, ax); ay = fmaf(e0.y, w0, ay);
            ax = fmaf(e1.x, w1, ax); ay = fmaf(e1.y, w1, ay);
        }
    }
    return make_float2(ax, ay);
}

template<int RES_>
__device__ __forceinline__ float2 hash_feat(const float2* __restrict__ tab,
                                            float px, float py, float pz)
{
    const Tri s = tri_setup<RES_>(px, py, pz);
    const uint32_t hy0 = (uint32_t)s.iy * P1;
    const uint32_t hz0 = (uint32_t)s.iz * P2;
    const uint32_t hy[2] = {hy0, hy0 + P1};
    const uint32_t hz[2] = {hz0, hz0 + P2};
    const uint32_t ux = (uint32_t)s.ix;
    float ax = 0.0f, ay = 0.0f;
#pragma unroll
    for (int k = 0; k < 2; ++k)
#pragma unroll
    for (int j = 0; j < 2; ++j) {
        const bool vyz = s.vy[j] && s.vz[k];
        const float wyz = s.wy[j] * s.wz[k];
        const uint32_t E = hy[j] ^ hz[k];
        const uint32_t J0 = (ux ^ E) & HMASK;          // in-bounds even for garbage coords
        const uint32_t J1 = ((ux + 1u) ^ E) & HMASK;   // w=0 masks invalid contributions
        const float w0 = (vyz && s.vx[0]) ? s.wx[0] * wyz : 0.0f;
        const float w1 = (vyz && s.vx[1]) ? s.wx[1] * wyz : 0.0f;
        if (!(ux & 1u)) {
            // ix even -> J1 == J0^1: both corners live in one aligned float2-pair
            const float4 q = *(const float4*)(tab + (J0 & ~1u));
            const float wl = (J0 & 1u) ? w1 : w0;      // weight for low entry
            const float wh = (J0 & 1u) ? w0 : w1;
            ax = fmaf(q.x, wl, ax); ay = fmaf(q.y, wl, ay);
            ax = fmaf(q.z, wh, ax); ay = fmaf(q.w, wh, ay);
        } else {
            const float2 e0 = tab[J0];
            const float2 e1 = tab[J1];
            ax = fmaf(e0.x, w0, ax); ay = fmaf(e0.y, w0, ay);
            ax = fmaf(e1.x, w1, ax); ay = fmaf(e1.y, w1, ay);
        }
    }
    return make_float2(ax, ay);
}

// ---- Kernel A: dense levels 0-7, writes lower 64B of each point's 128B ----
__global__ __launch_bounds__(BLOCK) void dense_kernel(
    const float* __restrict__ x, EmbPtrs embs, float4* __restrict__ out, int n)
{
    const int b = blockIdx.x * BLOCK + threadIdx.x;
    if (b >= n) return;
    const float px = x[3*b+0], py = x[3*b+1], pz = x[3*b+2];

    float2 f[8];
    f[0] = dense_feat<16>(embs.p[0], px, py, pz);
    f[1] = dense_feat<20>(embs.p[1], px, py, pz);
    f[2] = dense_feat<25>(embs.p[2], px, py, pz);
    f[3] = dense_feat<32>(embs.p[3], px, py, pz);
    f[4] = dense_feat<40>(embs.p[4], px, py, pz);
    f[5] = dense_feat<50>(embs.p[5], px, py, pz);
    f[6] = dense_feat<64>(embs.p[6], px, py, pz);
    f[7] = dense_feat<80>(embs.p[7], px, py, pz);

    float4* o = out + (size_t)b * 8;        // 64B aligned-contiguous
#pragma unroll
    for (int i = 0; i < 4; ++i)
        o[i] = make_float4(f[2*i].x, f[2*i].y, f[2*i+1].x, f[2*i+1].y);
}

// ---- One kernel per hash level, 2 points/thread; coalesced 8B stream out ----
template<int L>
__global__ __launch_bounds__(BLOCK) void hash_level_kernel(
    const float* __restrict__ x, const float2* __restrict__ tab,
    float2* __restrict__ ws, int n)
{
    const int h = (n + 1) >> 1;
    const int b = blockIdx.x * BLOCK + threadIdx.x;
    if (b >= h) return;
    ws[b] = hash_feat<kRes[L]>(tab, x[3*b+0], x[3*b+1], x[3*b+2]);
    const int p1 = b + h;
    if (p1 < n)
        ws[p1] = hash_feat<kRes[L]>(tab, x[3*p1+0], x[3*p1+1], x[3*p1+2]);
}

// ---- Merge: 8 level-major streams -> upper 64B; 2 points/thread, float4 reads ----
__global__ __launch_bounds__(BLOCK) void merge_kernel2(
    const float2* __restrict__ ws, float4* __restrict__ out, int n)
{
    const int t = blockIdx.x * BLOCK + threadIdx.x;      // n even: t < n/2
    if (t >= (n >> 1)) return;
    const int p0 = 2 * t;
    float4 q[8];
#pragma unroll
    for (int l = 0; l < 8; ++l)
        q[l] = *(const float4*)(ws + (size_t)l * n + p0);   // n even -> 16B aligned
    float4* o0 = out + (size_t)p0 * 8 + 4;
    float4* o1 = out + (size_t)(p0 + 1) * 8 + 4;
#pragma unroll
    for (int i = 0; i < 4; ++i) {
        o0[i] = make_float4(q[2*i].x, q[2*i].y, q[2*i+1].x, q[2*i+1].y);
        o1[i] = make_float4(q[2*i].z, q[2*i].w, q[2*i+1].z, q[2*i+1].w);
    }
}

__global__ __launch_bounds__(BLOCK) void merge_kernel1(
    const float2* __restrict__ ws, float4* __restrict__ out, int n)
{
    const int b = blockIdx.x * BLOCK + threadIdx.x;
    if (b >= n) return;
    float2 f[8];
#pragma unroll
    for (int l = 0; l < 8; ++l)
        f[l] = ws[(size_t)l * n + b];
    float4* o = out + (size_t)b * 8 + 4;
#pragma unroll
    for (int i = 0; i < 4; ++i)
        o[i] = make_float4(f[2*i].x, f[2*i].y, f[2*i+1].x, f[2*i+1].y);
}

// ---- Fallback if d_ws too small: single kernel, all levels ----
__global__ __launch_bounds__(BLOCK) void fallback_kernel(
    const float* __restrict__ x, EmbPtrs embs, float4* __restrict__ out, int n)
{
    const int b = blockIdx.x * BLOCK + threadIdx.x;
    if (b >= n) return;
    const float px = x[3*b+0], py = x[3*b+1], pz = x[3*b+2];
    float2 f[16];
    f[0]  = dense_feat<16 >(embs.p[0],  px, py, pz);
    f[1]  = dense_feat<20 >(embs.p[1],  px, py, pz);
    f[2]  = dense_feat<25 >(embs.p[2],  px, py, pz);
    f[3]  = dense_feat<32 >(embs.p[3],  px, py, pz);
    f[4]  = dense_feat<40 >(embs.p[4],  px, py, pz);
    f[5]  = dense_feat<50 >(embs.p[5],  px, py, pz);
    f[6]  = dense_feat<64 >(embs.p[6],  px, py, pz);
    f[7]  = dense_feat<80 >(embs.p[7],  px, py, pz);
    f[8]  = hash_feat<101>(embs.p[8],  px, py, pz);
    f[9]  = hash_feat<128>(embs.p[9],  px, py, pz);
    f[10] = hash_feat<161>(embs.p[10], px, py, pz);
    f[11] = hash_feat<203>(embs.p[11], px, py, pz);
    f[12] = hash_feat<256>(embs.p[12], px, py, pz);
    f[13] = hash_feat<322>(embs.p[13], px, py, pz);
    f[14] = hash_feat<406>(embs.p[14], px, py, pz);
    f[15] = hash_feat<512>(embs.p[15], px, py, pz);
    float4* o = out + (size_t)b * 8;
#pragma unroll
    for (int i = 0; i < 8; ++i)
        o[i] = make_float4(f[2*i].x, f[2*i].y, f[2*i+1].x, f[2*i+1].y);
}

extern "C" void kernel_launch(void* const* d_in, const int* in_sizes, int n_in,
                              void* d_out, int out_size, void* d_ws, size_t ws_size,
                              hipStream_t stream) {
    const float* x = (const float*)d_in[0];
    EmbPtrs embs;
    for (int l = 0; l < 16; ++l) embs.p[l] = (const float2*)d_in[1 + l];
    const int n = in_sizes[0] / 3;          // (B,3) fp32
    const int grid  = (n + BLOCK - 1) / BLOCK;
    const int hgrid = (((n + 1) >> 1) + BLOCK - 1) / BLOCK;
    float4* out = (float4*)d_out;

    const size_t need = (size_t)8 * (size_t)n * sizeof(float2);   // 64 MB @ n=1M
    if (ws_size >= need) {
        float2* ws = (float2*)d_ws;
        dense_kernel<<<grid, BLOCK, 0, stream>>>(x, embs, out, n);
        hash_level_kernel< 8><<<hgrid, BLOCK, 0, stream>>>(x, embs.p[ 8], ws + 0*(size_t)n, n);
        hash_level_kernel< 9><<<hgrid, BLOCK, 0, stream>>>(x, embs.p[ 9], ws + 1*(size_t)n, n);
        hash_level_kernel<10><<<hgrid, BLOCK, 0, stream>>>(x, embs.p[10], ws + 2*(size_t)n, n);
        hash_level_kernel<11><<<hgrid, BLOCK, 0, stream>>>(x, embs.p[11], ws + 3*(size_t)n, n);
        hash_level_kernel<12><<<hgrid, BLOCK, 0, stream>>>(x, embs.p[12], ws + 4*(size_t)n, n);
        hash_level_kernel<13><<<hgrid, BLOCK, 0, stream>>>(x, embs.p[13], ws + 5*(size_t)n, n);
        hash_level_kernel<14><<<hgrid, BLOCK, 0, stream>>>(x, embs.p[14], ws + 6*(size_t)n, n);
        hash_level_kernel<15><<<hgrid, BLOCK, 0, stream>>>(x, embs.p[15], ws + 7*(size_t)n, n);
        if ((n & 1) == 0)
            merge_kernel2<<<hgrid, BLOCK, 0, stream>>>(ws, out, n);
        else
            merge_kernel1<<<grid, BLOCK, 0, stream>>>(ws, out, n);
    } else {
        fallback_kernel<<<grid, BLOCK, 0, stream>>>(x, embs, out, n);
    }
}

// Round 9
// 635.978 us; speedup vs baseline: 1.1140x; 1.1140x over previous
//
#include <hip/hip_runtime.h>
#include <stdint.h>

// instant-ngp multilevel hash-grid encoding, MI355X — phase-split + LDS-staged
// small levels.
//
// R2: one kernel: 700us, FETCH 2.04GB (16 tables thrash L2).
// R4: grid.sync phases: FETCH 575MB but 2240us (barrier drain + 32B RMW).
// R5: kernel-per-hash-level + staged merge: 681us. dense=253us (32 VGPR, 68% occ).
// R6/R8: paired-load attempt: dense 285us — VGPR 112, occ 21%. REVERTED.
//   Lesson: occ 68->21% cost only +13% => bound is per-CU TA/TD divergent-gather
//   serialization (fixed-rate), not latency. All levels cost ~32-43us regardless
//   of table size/residency => hit location irrelevant, address count is king.
// R9 (this): move requests OFF the vmem address pipe: stage levels 0+1
//   (32KB+62.5KB=94.5KB) in LDS; LDS pipe is idle and serves random 8B gathers
//   far faster than TA serialization. Everything else = R5 known-good forms.

struct EmbPtrs { const float2* p[16]; };

constexpr int BLOCK  = 256;    // hash/merge/fallback block
constexpr int DBLOCK = 1024;   // dense block (1 block/CU due to LDS; 16 waves)
constexpr int L0N = 16*16*16;  // 4096 float2 = 32768 B
constexpr int L1N = 20*20*20;  // 8000 float2 = 64000 B
constexpr int kRes[16] = {16,20,25,32,40,50,64,80,101,128,161,203,256,322,406,512};
constexpr uint32_t P1 = 2654435761u, P2 = 805459861u;
constexpr uint32_t HMASK = (1u << 19) - 1u;

struct Tri {
    int ix, iy, iz;
    float wx[2], wy[2], wz[2];
    bool vx[2], vy[2], vz[2];
};

template<int RES_>
__device__ __forceinline__ Tri tri_setup(float px, float py, float pz)
{
    Tri s;
    const float rh = (float)RES_ * 0.5f;
    const float xp = (px + 1.0f) * rh - 0.5f;   // match reference op order
    const float yp = (py + 1.0f) * rh - 0.5f;
    const float zp = (pz + 1.0f) * rh - 0.5f;
    const float fx = floorf(xp), fy = floorf(yp), fz = floorf(zp);
    s.ix = (int)fx; s.iy = (int)fy; s.iz = (int)fz;
    const float tx = xp - fx, ty = yp - fy, tz = zp - fz;
    s.wx[0] = 1.0f - tx; s.wx[1] = tx;
    s.wy[0] = 1.0f - ty; s.wy[1] = ty;
    s.wz[0] = 1.0f - tz; s.wz[1] = tz;
    s.vx[0] = (s.ix   >= 0) && (s.ix   < RES_); s.vx[1] = (s.ix+1 >= 0) && (s.ix+1 < RES_);
    s.vy[0] = (s.iy   >= 0) && (s.iy   < RES_); s.vy[1] = (s.iy+1 >= 0) && (s.iy+1 < RES_);
    s.vz[0] = (s.iz   >= 0) && (s.iz   < RES_); s.vz[1] = (s.iz+1 >= 0) && (s.iz+1 < RES_);
    return s;
}

// PTR is either const float2* (global) or float2* derived from __shared__ —
// templated so the compiler keeps the LDS address space after inlining.
template<int RES_, typename PTR>
__device__ __forceinline__ float2 dense_feat(PTR tab, float px, float py, float pz)
{
    const Tri s = tri_setup<RES_>(px, py, pz);
    constexpr int r2 = RES_ * RES_;
    const int base = s.ix + s.iy * RES_ + s.iz * r2;
    float ax = 0.0f, ay = 0.0f;
#pragma unroll
    for (int k = 0; k < 2; ++k)
#pragma unroll
    for (int j = 0; j < 2; ++j)
#pragma unroll
    for (int i = 0; i < 2; ++i) {
        const bool v = s.vx[i] && s.vy[j] && s.vz[k];
        const uint32_t idx = v ? (uint32_t)(base + i + j*RES_ + k*r2) : 0u;
        const float w = v ? (s.wx[i]*s.wy[j]*s.wz[k]) : 0.0f;
        const float2 e = tab[idx];
        ax = fmaf(e.x, w, ax);
        ay = fmaf(e.y, w, ay);
    }
    return make_float2(ax, ay);
}

template<int RES_>
__device__ __forceinline__ float2 hash_feat(const float2* __restrict__ tab,
                                            float px, float py, float pz)
{
    const Tri s = tri_setup<RES_>(px, py, pz);
    const uint32_t hy0 = (uint32_t)s.iy * P1;
    const uint32_t hz0 = (uint32_t)s.iz * P2;
    const uint32_t hx[2] = {(uint32_t)s.ix, (uint32_t)s.ix + 1u};
    const uint32_t hy[2] = {hy0, hy0 + P1};
    const uint32_t hz[2] = {hz0, hz0 + P2};
    float ax = 0.0f, ay = 0.0f;
#pragma unroll
    for (int k = 0; k < 2; ++k)
#pragma unroll
    for (int j = 0; j < 2; ++j)
#pragma unroll
    for (int i = 0; i < 2; ++i) {
        const bool v = s.vx[i] && s.vy[j] && s.vz[k];
        uint32_t idx = (hx[i] ^ hy[j] ^ hz[k]) & HMASK;
        idx = v ? idx : 0u;
        const float w = v ? (s.wx[i]*s.wy[j]*s.wz[k]) : 0.0f;
        const float2 e = tab[idx];
        ax = fmaf(e.x, w, ax);
        ay = fmaf(e.y, w, ay);
    }
    return make_float2(ax, ay);
}

// ---- Dense levels 0-7; L0+L1 interpolated from LDS; writes lower 64B ----
__global__ __launch_bounds__(DBLOCK) void dense_kernel(
    const float* __restrict__ x, EmbPtrs embs, float4* __restrict__ out, int n)
{
    __shared__ float2 lds0[L0N];   // 32768 B
    __shared__ float2 lds1[L1N];   // 64000 B   (total 94.5 KB < 160 KB)

    {   // coalesced staging, float4 granularity; ALL threads participate
        const float4* g0 = (const float4*)embs.p[0];
        const float4* g1 = (const float4*)embs.p[1];
        float4* s0 = (float4*)lds0;
        float4* s1 = (float4*)lds1;
#pragma unroll 2
        for (int i = threadIdx.x; i < L0N/2; i += DBLOCK) s0[i] = g0[i];
#pragma unroll 4
        for (int i = threadIdx.x; i < L1N/2; i += DBLOCK) s1[i] = g1[i];
    }
    __syncthreads();

    const int b = blockIdx.x * DBLOCK + threadIdx.x;
    if (b >= n) return;
    const float px = x[3*b+0], py = x[3*b+1], pz = x[3*b+2];

    float2 f[8];
    f[0] = dense_feat<16>((const float2*)lds0, px, py, pz);   // LDS pipe
    f[1] = dense_feat<20>((const float2*)lds1, px, py, pz);   // LDS pipe
    f[2] = dense_feat<25>(embs.p[2], px, py, pz);
    f[3] = dense_feat<32>(embs.p[3], px, py, pz);
    f[4] = dense_feat<40>(embs.p[4], px, py, pz);
    f[5] = dense_feat<50>(embs.p[5], px, py, pz);
    f[6] = dense_feat<64>(embs.p[6], px, py, pz);
    f[7] = dense_feat<80>(embs.p[7], px, py, pz);

    float4* o = out + (size_t)b * 8;        // 64B aligned-contiguous
#pragma unroll
    for (int i = 0; i < 4; ++i)
        o[i] = make_float4(f[2*i].x, f[2*i].y, f[2*i+1].x, f[2*i+1].y);
}

// ---- One kernel per hash level (R5 form); coalesced 8B stream out ----
template<int L>
__global__ __launch_bounds__(BLOCK) void hash_level_kernel(
    const float* __restrict__ x, const float2* __restrict__ tab,
    float2* __restrict__ ws, int n)
{
    const int b = blockIdx.x * BLOCK + threadIdx.x;
    if (b >= n) return;
    ws[b] = hash_feat<kRes[L]>(tab, x[3*b+0], x[3*b+1], x[3*b+2]);
}

// ---- Merge: 8 level-major streams -> upper 64B of each point (R5 form) ----
__global__ __launch_bounds__(BLOCK) void merge_kernel(
    const float2* __restrict__ ws, float4* __restrict__ out, int n)
{
    const int b = blockIdx.x * BLOCK + threadIdx.x;
    if (b >= n) return;
    float2 f[8];
#pragma unroll
    for (int l = 0; l < 8; ++l)
        f[l] = ws[(size_t)l * n + b];
    float4* o = out + (size_t)b * 8 + 4;    // 64B aligned-contiguous
#pragma unroll
    for (int i = 0; i < 4; ++i)
        o[i] = make_float4(f[2*i].x, f[2*i].y, f[2*i+1].x, f[2*i+1].y);
}

// ---- Fallback if d_ws too small: single kernel, all levels ----
__global__ __launch_bounds__(BLOCK) void fallback_kernel(
    const float* __restrict__ x, EmbPtrs embs, float4* __restrict__ out, int n)
{
    const int b = blockIdx.x * BLOCK + threadIdx.x;
    if (b >= n) return;
    const float px = x[3*b+0], py = x[3*b+1], pz = x[3*b+2];
    float2 f[16];
    f[0]  = dense_feat<16 >(embs.p[0],  px, py, pz);
    f[1]  = dense_feat<20 >(embs.p[1],  px, py, pz);
    f[2]  = dense_feat<25 >(embs.p[2],  px, py, pz);
    f[3]  = dense_feat<32 >(embs.p[3],  px, py, pz);
    f[4]  = dense_feat<40 >(embs.p[4],  px, py, pz);
    f[5]  = dense_feat<50 >(embs.p[5],  px, py, pz);
    f[6]  = dense_feat<64 >(embs.p[6],  px, py, pz);
    f[7]  = dense_feat<80 >(embs.p[7],  px, py, pz);
    f[8]  = hash_feat<101>(embs.p[8],  px, py, pz);
    f[9]  = hash_feat<128>(embs.p[9],  px, py, pz);
    f[10] = hash_feat<161>(embs.p[10], px, py, pz);
    f[11] = hash_feat<203>(embs.p[11], px, py, pz);
    f[12] = hash_feat<256>(embs.p[12], px, py, pz);
    f[13] = hash_feat<322>(embs.p[13], px, py, pz);
    f[14] = hash_feat<406>(embs.p[14], px, py, pz);
    f[15] = hash_feat<512>(embs.p[15], px, py, pz);
    float4* o = out + (size_t)b * 8;
#pragma unroll
    for (int i = 0; i < 8; ++i)
        o[i] = make_float4(f[2*i].x, f[2*i].y, f[2*i+1].x, f[2*i+1].y);
}

extern "C" void kernel_launch(void* const* d_in, const int* in_sizes, int n_in,
                              void* d_out, int out_size, void* d_ws, size_t ws_size,
                              hipStream_t stream) {
    const float* x = (const float*)d_in[0];
    EmbPtrs embs;
    for (int l = 0; l < 16; ++l) embs.p[l] = (const float2*)d_in[1 + l];
    const int n = in_sizes[0] / 3;          // (B,3) fp32
    const int grid  = (n + BLOCK - 1) / BLOCK;
    const int dgrid = (n + DBLOCK - 1) / DBLOCK;
    float4* out = (float4*)d_out;

    const size_t need = (size_t)8 * (size_t)n * sizeof(float2);   // 64 MB @ n=1M
    if (ws_size >= need) {
        float2* ws = (float2*)d_ws;
        dense_kernel<<<dgrid, DBLOCK, 0, stream>>>(x, embs, out, n);
        hash_level_kernel< 8><<<grid, BLOCK, 0, stream>>>(x, embs.p[ 8], ws + 0*(size_t)n, n);
        hash_level_kernel< 9><<<grid, BLOCK, 0, stream>>>(x, embs.p[ 9], ws + 1*(size_t)n, n);
        hash_level_kernel<10><<<grid, BLOCK, 0, stream>>>(x, embs.p[10], ws + 2*(size_t)n, n);
        hash_level_kernel<11><<<grid, BLOCK, 0, stream>>>(x, embs.p[11], ws + 3*(size_t)n, n);
        hash_level_kernel<12><<<grid, BLOCK, 0, stream>>>(x, embs.p[12], ws + 4*(size_t)n, n);
        hash_level_kernel<13><<<grid, BLOCK, 0, stream>>>(x, embs.p[13], ws + 5*(size_t)n, n);
        hash_level_kernel<14><<<grid, BLOCK, 0, stream>>>(x, embs.p[14], ws + 6*(size_t)n, n);
        hash_level_kernel<15><<<grid, BLOCK, 0, stream>>>(x, embs.p[15], ws + 7*(size_t)n, n);
        merge_kernel<<<grid, BLOCK, 0, stream>>>(ws, out, n);
    } else {
        fallback_kernel<<<grid, BLOCK, 0, stream>>>(x, embs, out, n);
    }
}